// Round 20
// baseline (6721.881 us; speedup 1.0000x reference)
//
#include <hip/hip_runtime.h>
#include <hip/hip_bf16.h>

#define S 1024
#define D 1024
#define DI 2048
#define NSTATE 16
#define DTR 64
#define XPD 96      // DT_RANK + 2N
#define NL 48
#define CARD 2048
#define KTOK 4

typedef __attribute__((ext_vector_type(8))) short bf16x8;
typedef __attribute__((ext_vector_type(4))) float f32x4;
typedef __attribute__((ext_vector_type(4))) unsigned short us4;
struct __align__(16) US8 { unsigned long long a, b; };

__device__ __forceinline__ unsigned short f2bf(float f) {
    unsigned u = __builtin_bit_cast(unsigned, f);
    return (unsigned short)((u + 0x7fffu + ((u >> 16) & 1u)) >> 16);
}
__device__ __forceinline__ float bf2f(unsigned short u) {
    return __builtin_bit_cast(float, (unsigned)u << 16);
}
__device__ __forceinline__ float fsilu(float x) { return x / (1.f + __expf(-x)); }
__device__ __forceinline__ float fsoftplus(float x) {
    return fmaxf(x, 0.f) + log1pf(__expf(-fabsf(x)));
}
template<int CTRL>
__device__ __forceinline__ float dpp_add(float v) {
    int m = __builtin_amdgcn_update_dpp(0, __builtin_bit_cast(int, v), CTRL, 0xF, 0xF, true);
    return v + __builtin_bit_cast(float, m);
}
__device__ __forceinline__ void gload_lds16(const void* g, void* l) {
    __builtin_amdgcn_global_load_lds((const __attribute__((address_space(1))) void*)g,
                                     (__attribute__((address_space(3))) void*)l, 16, 0, 0);
}
template<int N> __device__ __forceinline__ void wait_vm() {
    if constexpr (N == 0)      asm volatile("s_waitcnt vmcnt(0)" ::: "memory");
    else if constexpr (N == 3) asm volatile("s_waitcnt vmcnt(3)" ::: "memory");
    else if constexpr (N == 4) asm volatile("s_waitcnt vmcnt(4)" ::: "memory");
    else if constexpr (N == 6) asm volatile("s_waitcnt vmcnt(6)" ::: "memory");
    else                       asm volatile("s_waitcnt vmcnt(8)" ::: "memory");
}

// ------------- fp32 -> bf16 convert, 4 ranges (sizes in 8-elem units, long grid) -------------
__global__ __launch_bounds__(256) void cvt4_kernel(const float* __restrict__ a, long NA,
                                                   const float* __restrict__ b, long NB,
                                                   const float* __restrict__ c, long NC,
                                                   const float* __restrict__ d, long ND,
                                                   unsigned short* __restrict__ oa,
                                                   unsigned short* __restrict__ ob,
                                                   unsigned short* __restrict__ oc,
                                                   unsigned short* __restrict__ od) {
    long i = (long)blockIdx.x * 256 + threadIdx.x;
    const float* src; unsigned short* dst; long off;
    if (i < NA)                    { src = a; dst = oa; off = i; }
    else if (i < NA + NB)          { src = b; dst = ob; off = i - NA; }
    else if (i < NA + NB + NC)     { src = c; dst = oc; off = i - NA - NB; }
    else                            { src = d; dst = od; off = i - NA - NB - NC; }
    f32x4 v0 = *(const f32x4*)&src[off * 8];
    f32x4 v1 = *(const f32x4*)&src[off * 8 + 4];
    US8 pk;
    pk.a = (unsigned long long)f2bf(v0[0]) | ((unsigned long long)f2bf(v0[1]) << 16)
         | ((unsigned long long)f2bf(v0[2]) << 32) | ((unsigned long long)f2bf(v0[3]) << 48);
    pk.b = (unsigned long long)f2bf(v1[0]) | ((unsigned long long)f2bf(v1[1]) << 16)
         | ((unsigned long long)f2bf(v1[2]) << 32) | ((unsigned long long)f2bf(v1[3]) << 48);
    *(US8*)&dst[off * 8] = pk;
}

// ---------------- embedding: x[s][d] = sum_k emb_W[k][seq[k][s]][d] ----------------
__global__ __launch_bounds__(256) void embed_kernel(const int* __restrict__ seq,
                                                    const float* __restrict__ embW,
                                                    float* __restrict__ x) {
    int s = blockIdx.x, t = threadIdx.x;
    f32x4 acc = (f32x4)0.f;
#pragma unroll
    for (int k = 0; k < KTOK; ++k) {
        int tok = seq[k * S + s];
        const f32x4 v = *(const f32x4*)&embW[((size_t)k * CARD + tok) * D + t * 4];
        acc += v;
    }
    *(f32x4*)&x[(size_t)s * D + t * 4] = acc;
}

// ---------------- RMSNorm over rows of length D, bf16 output ----------------
__global__ __launch_bounds__(256) void rmsnorm_kernel(const float* __restrict__ x,
                                                      const float* __restrict__ w,
                                                      unsigned short* __restrict__ o) {
    int row = blockIdx.x, t = threadIdx.x;
    f32x4 v = *(const f32x4*)&x[(size_t)row * D + t * 4];
    float ss = v[0]*v[0] + v[1]*v[1] + v[2]*v[2] + v[3]*v[3];
#pragma unroll
    for (int off = 32; off >= 1; off >>= 1) ss += __shfl_xor(ss, off);
    __shared__ float red[4];
    int wave = t >> 6, lane = t & 63;
    if (lane == 0) red[wave] = ss;
    __syncthreads();
    ss = red[0] + red[1] + red[2] + red[3];
    float rs = rsqrtf(ss * (1.f / D) + 1e-5f);
    f32x4 wv = *(const f32x4*)&w[t * 4];
    unsigned long long pk = 0;
#pragma unroll
    for (int j = 0; j < 4; ++j)
        pk |= (unsigned long long)f2bf(v[j] * rs * wv[j]) << (16 * j);
    *(unsigned long long*)&o[(size_t)row * D + t * 4] = pk;
}

// ------- out_proj reduce (2 partials) + residual add + RMSNorm (fused) -------
__global__ __launch_bounds__(256) void outred_rms_kernel(const float* __restrict__ part,
                                                         const float* __restrict__ xin,
                                                         float* __restrict__ xout,
                                                         const float* __restrict__ w,
                                                         unsigned short* __restrict__ o) {
    int row = blockIdx.x, t = threadIdx.x;
    size_t base = (size_t)row * D + t * 4;
    f32x4 v = *(const f32x4*)&xin[base];
#pragma unroll
    for (int j = 0; j < 2; ++j)
        v += *(const f32x4*)&part[(size_t)j * (S * D) + base];
    *(f32x4*)&xout[base] = v;
    float ss = v[0]*v[0] + v[1]*v[1] + v[2]*v[2] + v[3]*v[3];
#pragma unroll
    for (int off = 32; off >= 1; off >>= 1) ss += __shfl_xor(ss, off);
    __shared__ float red[4];
    int wave = t >> 6, lane = t & 63;
    if (lane == 0) red[wave] = ss;
    __syncthreads();
    ss = red[0] + red[1] + red[2] + red[3];
    float rs = rsqrtf(ss * (1.f / D) + 1e-5f);
    f32x4 wv = *(const f32x4*)&w[t * 4];
    unsigned long long pk = 0;
#pragma unroll
    for (int j = 0; j < 4; ++j)
        pk |= (unsigned long long)f2bf(v[j] * rs * wv[j]) << (16 * j);
    *(unsigned long long*)&o[base] = pk;
}

// ------- x_proj reduce: ssm = sum of 16 partial slabs; also bf16 copy -------
__global__ __launch_bounds__(256) void ssm_reduce_kernel(const float* __restrict__ part,
                                                         float* __restrict__ ssm,
                                                         unsigned short* __restrict__ ssmb) {
    int i = blockIdx.x * 256 + threadIdx.x;    // < S*XPD
    float a = 0.f;
#pragma unroll
    for (int j = 0; j < 16; ++j)
        a += part[(size_t)j * (S * XPD) + i];
    ssm[i] = a;
    ssmb[i] = f2bf(a);
}

// ---------- causal depthwise conv1d (k=4) + bias + silu (bf16 out) ----------
__global__ __launch_bounds__(256) void conv_silu_kernel(const float* __restrict__ proj,
                                                        const float* __restrict__ cw,
                                                        const float* __restrict__ cb,
                                                        unsigned short* __restrict__ ub) {
    int idx = blockIdx.x * 256 + threadIdx.x;   // s*DI + c
    int s = idx >> 11, c = idx & (DI - 1);
    f32x4 w = *(const f32x4*)&cw[c * 4];
    float acc = cb[c];
#pragma unroll
    for (int t = 0; t < 4; ++t) {
        int ss = s - 3 + t;
        if (ss >= 0) acc = fmaf(w[t], proj[(size_t)ss * 4096 + c], acc);
    }
    ub[idx] = f2bf(acc * (1.f / (1.f + __expf(-acc))));
}

// ------- scan2 + fused dt-projection; ushort4 u-staging; serial unrolls 16/8 -------
// block: 1024 thr = 16 chunks x 4 d x 16 n; grid = DI/4 = 512 blocks. LDS 56KB, 2 blocks/CU.
__global__ __launch_bounds__(1024, 2) void scan2_kernel(const unsigned short* __restrict__ ssmb,
                                                        const unsigned short* __restrict__ dtWb,
                                                        const float* __restrict__ dtb,
                                                        const unsigned short* __restrict__ ub,
                                                        const float* __restrict__ ssm,
                                                        const float* __restrict__ proj,
                                                        const float* __restrict__ A_log,
                                                        const float* __restrict__ Dsk,
                                                        unsigned short* __restrict__ yfb) {
    __shared__ float sdu[S * 4 * 2];   // [s][dl][{dt,u}]  32KB
    __shared__ float sP[1024], sQ[1024];
    __shared__ float sy[S * 4];        // ungated y        16KB

    const int tid = threadIdx.x;
    const int d0 = blockIdx.x * 4;
    const int chunk = tid >> 6;        // wave index = chunk (16 chunks of 64 steps)
    const int lane = tid & 63;
    const int dl = (tid >> 4) & 3;
    const int n = tid & 15;
    const int sbase = chunk * 64;

    // stage u: one 8B ushort4 load per thread (s = tid, all 4 channels)
    {
        us4 uv = *(const us4*)&ub[(size_t)tid * DI + d0];
#pragma unroll
        for (int j = 0; j < 4; ++j)
            sdu[(tid * 4 + j) * 2 + 1] = bf2f(uv[j]);
    }

    // dt = softplus(ssmb[:, :64] @ dtWb[d0..d0+3]^T + dtb) — per wave, own 64 s-rows.
    {
        const int lr = lane & 15;
        const int lk = (lane >> 4) << 3;
        f32x4 dacc[4];
#pragma unroll
        for (int m = 0; m < 4; ++m) dacc[m] = (f32x4)0.f;
        bf16x8 wf0 = *(const bf16x8*)&dtWb[(size_t)(d0 + lr) * DTR + lk];
        bf16x8 wf1 = *(const bf16x8*)&dtWb[(size_t)(d0 + lr) * DTR + 32 + lk];
#pragma unroll
        for (int m = 0; m < 4; ++m) {
            const unsigned short* arow = &ssmb[(size_t)(sbase + m * 16 + lr) * XPD];
            bf16x8 a0 = *(const bf16x8*)&arow[lk];
            bf16x8 a1 = *(const bf16x8*)&arow[32 + lk];
            dacc[m] = __builtin_amdgcn_mfma_f32_16x16x32_bf16(a0, wf0, dacc[m], 0, 0, 0);
            dacc[m] = __builtin_amdgcn_mfma_f32_16x16x32_bf16(a1, wf1, dacc[m], 0, 0, 0);
        }
        if (lr < 4) {
            float bias = dtb[d0 + lr];
            const int rb = (lane >> 4) << 2;
#pragma unroll
            for (int m = 0; m < 4; ++m)
#pragma unroll
                for (int j = 0; j < 4; ++j) {
                    int sl = sbase + m * 16 + rb + j;
                    sdu[(sl * 4 + lr) * 2 + 0] = fsoftplus(dacc[m][j] + bias);
                }
        }
    }
    const float Av = -__expf(A_log[(d0 + dl) * NSTATE + n]);
    const float Dv = Dsk[d0 + dl];
    __syncthreads();

    // pass A: local scan from zero + product of dA (unroll 16: batch loads, overlap exps)
    float h = 0.f, P = 1.f;
#pragma unroll 16
    for (int i = 0; i < 64; ++i) {
        int s = sbase + i;
        float2 du = *(const float2*)&sdu[(s * 4 + dl) * 2];
        float Bs  = ssm[s * XPD + DTR + n];
        float dA  = __expf(du.x * Av);
        P *= dA;
        h = fmaf(dA, h, du.x * du.y * Bs);
    }
    const int pqb = (dl * 16 + n) * 16;
    sP[pqb + chunk] = P;
    sQ[pqb + chunk] = h;
    __syncthreads();
    float hi = 0.f;
    for (int j = 0; j < chunk; ++j) hi = fmaf(sP[pqb + j], hi, sQ[pqb + j]);
    // pass B: true scan, DPP tree-sum (unroll 8: overlap 8 independent DPP chains)
    h = hi;
#pragma unroll 8
    for (int i = 0; i < 64; ++i) {
        int s = sbase + i;
        float2 du = *(const float2*)&sdu[(s * 4 + dl) * 2];
        float Bs  = ssm[s * XPD + DTR + n];
        float Cs  = ssm[s * XPD + DTR + NSTATE + n];
        float dA  = __expf(du.x * Av);
        h = fmaf(dA, h, du.x * du.y * Bs);
        float pc = h * Cs;
        pc = dpp_add<0xB1>(pc);    // quad_perm xor1
        pc = dpp_add<0x4E>(pc);    // quad_perm xor2
        pc = dpp_add<0x124>(pc);   // row_ror:4
        pc = dpp_add<0x128>(pc);   // row_ror:8 -> full 16-lane sum
        if (n == 0)
            sy[s * 4 + dl] = pc + du.y * Dv;
    }
    __syncthreads();
    // epilogue: gate + store, batched (thread = s row)
    {
        int s = tid;
        f32x4 yv = *(const f32x4*)&sy[s * 4];
        f32x4 g  = *(const f32x4*)&proj[(size_t)s * 4096 + 2048 + d0];
        unsigned long long pk = 0;
#pragma unroll
        for (int j = 0; j < 4; ++j)
            pk |= (unsigned long long)f2bf(yv[j] * fsilu(g[j])) << (16 * j);
        *(unsigned long long*)&yfb[(size_t)s * DI + d0] = pk;
    }
}

// ---------------- GEMM: C(1024 x N) = A(1024 x K, lda) * Wb(N x K)^T ----------------
// bf16 MFMA 16x16x32, (MR*32)x(NR*32) tile, 4 waves (2x2). LDS XOR-swizzled.
// EPI: 0 store, 1 softplus(acc+bias), 3 bias+store z-batched, 5 partial-slab store (split-K)
// ABF16: A bf16 (gload_lds) else fp32 (reg-stage+convert)
// DBUF: 3-buffer, prefetch-distance-2, counted-vmcnt pipeline (BM in {64,128}, BN=128, bf16 A)
template<int MR, int NR, int EPI, int KSPLIT, int ABF16, int DBUF>
__global__ __launch_bounds__(256) void gemm_bt(const void* __restrict__ Av, int lda,
                                               const unsigned short* __restrict__ W,
                                               float* __restrict__ C,
                                               int K, int N,
                                               const float* __restrict__ bias) {
    constexpr int BM = MR * 32;
    constexpr int BN = NR * 32;
    static_assert(DBUF == 0 || ((BM == 64 || BM == 128) && BN == 128 && ABF16 == 1), "dbuf shape");
    constexpr int NBUF = DBUF ? 3 : 1;
    __shared__ unsigned short As[NBUF][BM][32];
    __shared__ unsigned short Ws[NBUF][BN][32];
    const int tid = threadIdx.x;
    const int lane = tid & 63;
    const int wave = tid >> 6;
    const int wr = wave >> 1, wc = wave & 1;
    const int m0 = blockIdx.y * BM;
    const int n0 = blockIdx.x * BN;
    const unsigned short* Wp = W;
    const float* biasp = bias;
    float* Cp = C;
    if (EPI == 3) {
        size_t z = blockIdx.z;
        Wp += z * (size_t)N * K;
        Cp += z * (size_t)1024 * N;
        biasp += z * N;
    }
    if (EPI == 5)
        Cp = C + (size_t)blockIdx.z * 1024 * N;
    f32x4 acc[MR][NR];
#pragma unroll
    for (int m = 0; m < MR; ++m)
#pragma unroll
        for (int n = 0; n < NR; ++n) acc[m][n] = (f32x4)0.f;

    const int lr = lane & 15;
    const int lkp = (((lane >> 4) ^ ((lr >> 1) & 3)) << 3);
    const int grow = lane >> 2;
    const int gcol = (((lane & 3) ^ ((lane >> 3) & 3)) << 3);

    const int kc = (KSPLIT > 1) ? blockIdx.z : 0;
    const int Kc = K / KSPLIT;
    const int kbeg = kc * Kc;

    if constexpr (DBUF) {
        const unsigned short* Ab = (const unsigned short*)Av;
        const int nt = Kc >> 5;
        constexpr int L = BM / 64 + 2;          // per-thread gloads per tile
        auto ISSUE = [&](int t, int buf) {
            const int k0 = kbeg + t * 32;
#pragma unroll
            for (int u2 = wave; u2 < BM / 16; u2 += 4)
                gload_lds16(&Ab[(size_t)(m0 + u2 * 16 + grow) * lda + k0 + gcol],
                            &As[buf][u2 * 16][0]);
#pragma unroll
            for (int u2 = wave; u2 < BN / 16; u2 += 4)
                gload_lds16(&Wp[(size_t)(n0 + u2 * 16 + grow) * K + k0 + gcol],
                            &Ws[buf][u2 * 16][0]);
        };
        ISSUE(0, 0);
        if (nt > 1) ISSUE(1, 1);
        int nb = 2;
        int cb2 = 0;
        for (int t = 0; t < nt; ++t) {
            if (t + 2 < nt) {
                ISSUE(t + 2, nb);
                if (++nb == 3) nb = 0;
            }
            const int rem = nt - 1 - t;
            if (rem >= 2)      wait_vm<2 * L>();
            else if (rem == 1) wait_vm<L>();
            else               wait_vm<0>();
            __builtin_amdgcn_s_barrier();
            bf16x8 af[MR], wf[NR];
#pragma unroll
            for (int m = 0; m < MR; ++m)
                af[m] = *(const bf16x8*)&As[cb2][wr * (MR * 16) + m * 16 + lr][lkp];
#pragma unroll
            for (int n = 0; n < NR; ++n)
                wf[n] = *(const bf16x8*)&Ws[cb2][wc * (NR * 16) + n * 16 + lr][lkp];
            asm volatile("s_waitcnt lgkmcnt(0)" ::: "memory");
            __builtin_amdgcn_s_barrier();
            if (++cb2 == 3) cb2 = 0;
#pragma unroll
            for (int m = 0; m < MR; ++m)
#pragma unroll
                for (int n = 0; n < NR; ++n)
                    acc[m][n] = __builtin_amdgcn_mfma_f32_16x16x32_bf16(af[m], wf[n], acc[m][n], 0, 0, 0);
        }
    } else {
        for (int k0 = kbeg; k0 < kbeg + Kc; k0 += 32) {
            __syncthreads();
            if (ABF16) {
                const unsigned short* Ab = (const unsigned short*)Av;
#pragma unroll
                for (int u2 = wave; u2 < BM / 16; u2 += 4)
                    gload_lds16(&Ab[(size_t)(m0 + u2 * 16 + grow) * lda + k0 + gcol],
                                &As[0][u2 * 16][0]);
            } else {
                const float* Af = (const float*)Av;
#pragma unroll
                for (int i = 0; i < BM / 32; ++i) {
                    int idx = tid + i * 256;
                    int row = idx >> 3, c4 = (idx & 7) << 2;
                    f32x4 v = *(const f32x4*)&Af[(size_t)(m0 + row) * lda + k0 + c4];
                    unsigned long long pk = (unsigned long long)f2bf(v[0])
                                          | ((unsigned long long)f2bf(v[1]) << 16)
                                          | ((unsigned long long)f2bf(v[2]) << 32)
                                          | ((unsigned long long)f2bf(v[3]) << 48);
                    int sl = (idx & 7) >> 1, hf = (idx & 7) & 1;
                    int p = sl ^ ((row >> 1) & 3);
                    *(unsigned long long*)&As[0][row][p * 8 + hf * 4] = pk;
                }
            }
#pragma unroll
            for (int u2 = wave; u2 < BN / 16; u2 += 4)
                gload_lds16(&Wp[(size_t)(n0 + u2 * 16 + grow) * K + k0 + gcol],
                            &Ws[0][u2 * 16][0]);
            __syncthreads();
            bf16x8 af[MR], wf[NR];
#pragma unroll
            for (int m = 0; m < MR; ++m)
                af[m] = *(const bf16x8*)&As[0][wr * (MR * 16) + m * 16 + lr][lkp];
#pragma unroll
            for (int n = 0; n < NR; ++n)
                wf[n] = *(const bf16x8*)&Ws[0][wc * (NR * 16) + n * 16 + lr][lkp];
#pragma unroll
            for (int m = 0; m < MR; ++m)
#pragma unroll
                for (int n = 0; n < NR; ++n)
                    acc[m][n] = __builtin_amdgcn_mfma_f32_16x16x32_bf16(af[m], wf[n], acc[m][n], 0, 0, 0);
        }
    }

    const int mo = m0 + wr * (MR * 16);
    const int no = n0 + wc * (NR * 16);
    const int rbase = (lane >> 4) << 2;
#pragma unroll
    for (int m = 0; m < MR; ++m) {
#pragma unroll
        for (int n = 0; n < NR; ++n) {
            int col = no + n * 16 + lr;
#pragma unroll
            for (int j = 0; j < 4; ++j) {
                int row = mo + m * 16 + rbase + j;
                float v = acc[m][n][j];
                if (EPI == 1) v = fsoftplus(v + biasp[col]);
                else if (EPI == 3) v += biasp[col];
                Cp[(size_t)row * N + col] = v;
            }
        }
    }
}

// per-layer weight element counts
#define IN_E   ((size_t)4096 * 1024)
#define OUT_E  ((size_t)1024 * 2048)
#define X_E    ((size_t)XPD * 2048)
#define DT_E   ((size_t)2048 * 64)
#define HEAD_E ((size_t)KTOK * CARD * 1024)

extern "C" void kernel_launch(void* const* d_in, const int* in_sizes, int n_in,
                              void* d_out, int out_size, void* d_ws, size_t ws_size,
                              hipStream_t stream) {
    const int*   seq     = (const int*)d_in[0];
    const float* embW    = (const float*)d_in[1];
    const float* norm_w  = (const float*)d_in[2];
    const float* in_W    = (const float*)d_in[3];
    const float* conv_w  = (const float*)d_in[4];
    const float* conv_b  = (const float*)d_in[5];
    const float* x_W     = (const float*)d_in[6];
    const float* dt_W    = (const float*)d_in[7];
    const float* dt_b    = (const float*)d_in[8];
    const float* A_log   = (const float*)d_in[9];
    const float* D_skip  = (const float*)d_in[10];
    const float* out_W   = (const float*)d_in[11];
    const float* normf_w = (const float*)d_in[12];
    const float* head_W  = (const float*)d_in[13];
    const float* head_b  = (const float*)d_in[14];

    float* ws   = (float*)d_ws;
    float* x    = ws;                                  // S*D f32
    float* proj = x    + (size_t)S * D;                // S*4096 f32 (alias: out_proj partials 2x S*D)
    float* ssm  = proj + (size_t)S * 4096;             // S*96 (pad 128) f32
    float* xpart = ssm + (size_t)S * 128;              // 16 slabs of S*XPD f32 (6MB; region is S*DI f32)
    unsigned short* hnb  = (unsigned short*)(xpart + (size_t)S * DI);  // S*D bf16
    unsigned short* ub   = hnb  + (size_t)S * D;                       // S*DI bf16
    unsigned short* yfb  = ub   + (size_t)S * DI;                      // S*DI bf16
    unsigned short* ssmb = yfb  + (size_t)S * DI;                      // S*128 bf16
    unsigned short* wbase = ssmb + (size_t)S * 128;
    float* opart = proj;   // 2 slabs of S*D (8MB) — proj dead after scan reads gate

    size_t actBytes = (char*)wbase - (char*)ws;
    size_t perLayerE = IN_E + OUT_E + X_E + DT_E;
    bool bulk = ws_size >= actBytes + (48 * perLayerE + HEAD_E) * 2 + 256;

    unsigned short* inWb, *outWb, *xWb, *dtWb, *headWb;
    size_t strIn, strOut, strX, strDt;
    if (bulk) {
        inWb  = wbase;
        outWb = inWb  + 48 * IN_E;
        xWb   = outWb + 48 * OUT_E;
        dtWb  = xWb   + 48 * X_E;
        headWb = dtWb + 48 * DT_E;
        strIn = IN_E; strOut = OUT_E; strX = X_E; strDt = DT_E;
    } else {
        inWb  = wbase;
        outWb = inWb  + IN_E;
        xWb   = outWb + OUT_E;
        dtWb  = xWb   + X_E;
        headWb = dtWb + DT_E;
        strIn = strOut = strX = strDt = 0;
    }

    embed_kernel<<<S, 256, 0, stream>>>(seq, embW, x);
    rmsnorm_kernel<<<S, 256, 0, stream>>>(x, norm_w, hnb);   // layer 0 norm
    cvt4_kernel<<<(unsigned)(HEAD_E / 8 / 256), 256, 0, stream>>>(
        head_W, (long)(HEAD_E / 8), nullptr, 0, nullptr, 0, nullptr, 0,
        headWb, nullptr, nullptr, nullptr);
    if (bulk) {
        long na = (long)(48 * IN_E / 8), nb = (long)(48 * OUT_E / 8);
        long nc = (long)(48 * X_E / 8),  nd = (long)(48 * DT_E / 8);
        cvt4_kernel<<<(unsigned)((na + nb + nc + nd) / 256), 256, 0, stream>>>(
            in_W, na, out_W, nb, x_W, nc, dt_W, nd, inWb, outWb, xWb, dtWb);
    }

    for (int l = 0; l < NL; ++l) {
        if (!bulk) {
            cvt4_kernel<<<(unsigned)(perLayerE / 8 / 256), 256, 0, stream>>>(
                in_W + (size_t)l * IN_E, (long)(IN_E / 8),
                out_W + (size_t)l * OUT_E, (long)(OUT_E / 8),
                x_W + (size_t)l * X_E, (long)(X_E / 8),
                dt_W + (size_t)l * DT_E, (long)(DT_E / 8),
                inWb, outWb, xWb, dtWb);
        }
        // in_proj: 64x128 tiles, 512 blocks (2/CU), 3-deep pipeline
        gemm_bt<2, 4, 0, 1, 1, 1><<<dim3(32, 16), 256, 0, stream>>>(hnb, D,
            inWb + (size_t)l * strIn, proj, D, 4096, nullptr);
        conv_silu_kernel<<<(S * DI) / 256, 256, 0, stream>>>(proj,
            conv_w + (size_t)l * DI * 4, conv_b + (size_t)l * DI, ub);
        // x_proj: bf16 A, 64x96 tiles, KSPLIT=16 -> 256 blocks
        gemm_bt<2, 3, 5, 16, 1, 0><<<dim3(1, 16, 16), 256, 0, stream>>>(ub, DI,
            xWb + (size_t)l * strX, xpart, DI, XPD, nullptr);
        ssm_reduce_kernel<<<(S * XPD) / 256, 256, 0, stream>>>(xpart, ssm, ssmb);
        scan2_kernel<<<DI / 4, 1024, 0, stream>>>(ssmb, dtWb + (size_t)l * strDt,
            dt_b + (size_t)l * DI, ub, ssm, proj,
            A_log + (size_t)l * DI * NSTATE, D_skip + (size_t)l * DI, yfb);
        // out_proj: 64x128 tiles, KSPLIT=2 -> 256 blocks, 2 partial slabs
        gemm_bt<2, 4, 5, 2, 1, 1><<<dim3(8, 16, 2), 256, 0, stream>>>(yfb, DI,
            outWb + (size_t)l * strOut, opart, DI, D, nullptr);
        outred_rms_kernel<<<S, 256, 0, stream>>>(opart, x, x,
            (l + 1 < NL) ? (norm_w + (size_t)(l + 1) * D) : normf_w, hnb);
    }

    gemm_bt<4, 4, 3, 1, 1, 1><<<dim3(16, 8, 4), 256, 0, stream>>>(hnb, D, headWb,
        (float*)d_out, D, CARD, head_b);
}

// Round 21
// 6167.822 us; speedup vs baseline: 1.0898x; 1.0898x over previous
//
#include <hip/hip_runtime.h>
#include <hip/hip_bf16.h>

#define S 1024
#define D 1024
#define DI 2048
#define NSTATE 16
#define DTR 64
#define XPD 96      // DT_RANK + 2N
#define NL 48
#define CARD 2048
#define KTOK 4

typedef __attribute__((ext_vector_type(8))) short bf16x8;
typedef __attribute__((ext_vector_type(4))) float f32x4;
typedef __attribute__((ext_vector_type(4))) unsigned short us4;
struct __align__(16) US8 { unsigned long long a, b; };

__device__ __forceinline__ unsigned short f2bf(float f) {
    unsigned u = __builtin_bit_cast(unsigned, f);
    return (unsigned short)((u + 0x7fffu + ((u >> 16) & 1u)) >> 16);
}
__device__ __forceinline__ float bf2f(unsigned short u) {
    return __builtin_bit_cast(float, (unsigned)u << 16);
}
__device__ __forceinline__ float fsilu(float x) { return x / (1.f + __expf(-x)); }
__device__ __forceinline__ float fsoftplus(float x) {
    return fmaxf(x, 0.f) + log1pf(__expf(-fabsf(x)));
}
template<int CTRL>
__device__ __forceinline__ float dpp_add(float v) {
    int m = __builtin_amdgcn_update_dpp(0, __builtin_bit_cast(int, v), CTRL, 0xF, 0xF, true);
    return v + __builtin_bit_cast(float, m);
}
__device__ __forceinline__ void gload_lds16(const void* g, void* l) {
    __builtin_amdgcn_global_load_lds((const __attribute__((address_space(1))) void*)g,
                                     (__attribute__((address_space(3))) void*)l, 16, 0, 0);
}
template<int N> __device__ __forceinline__ void wait_vm() {
    if constexpr (N == 0)      asm volatile("s_waitcnt vmcnt(0)" ::: "memory");
    else if constexpr (N == 3) asm volatile("s_waitcnt vmcnt(3)" ::: "memory");
    else if constexpr (N == 4) asm volatile("s_waitcnt vmcnt(4)" ::: "memory");
    else if constexpr (N == 6) asm volatile("s_waitcnt vmcnt(6)" ::: "memory");
    else                       asm volatile("s_waitcnt vmcnt(8)" ::: "memory");
}

// ------------- fp32 -> bf16 convert, 4 ranges (sizes in 8-elem units, long grid) -------------
__global__ __launch_bounds__(256) void cvt4_kernel(const float* __restrict__ a, long NA,
                                                   const float* __restrict__ b, long NB,
                                                   const float* __restrict__ c, long NC,
                                                   const float* __restrict__ d, long ND,
                                                   unsigned short* __restrict__ oa,
                                                   unsigned short* __restrict__ ob,
                                                   unsigned short* __restrict__ oc,
                                                   unsigned short* __restrict__ od) {
    long i = (long)blockIdx.x * 256 + threadIdx.x;
    const float* src; unsigned short* dst; long off;
    if (i < NA)                    { src = a; dst = oa; off = i; }
    else if (i < NA + NB)          { src = b; dst = ob; off = i - NA; }
    else if (i < NA + NB + NC)     { src = c; dst = oc; off = i - NA - NB; }
    else                            { src = d; dst = od; off = i - NA - NB - NC; }
    f32x4 v0 = *(const f32x4*)&src[off * 8];
    f32x4 v1 = *(const f32x4*)&src[off * 8 + 4];
    US8 pk;
    pk.a = (unsigned long long)f2bf(v0[0]) | ((unsigned long long)f2bf(v0[1]) << 16)
         | ((unsigned long long)f2bf(v0[2]) << 32) | ((unsigned long long)f2bf(v0[3]) << 48);
    pk.b = (unsigned long long)f2bf(v1[0]) | ((unsigned long long)f2bf(v1[1]) << 16)
         | ((unsigned long long)f2bf(v1[2]) << 32) | ((unsigned long long)f2bf(v1[3]) << 48);
    *(US8*)&dst[off * 8] = pk;
}

// ---------------- embedding: x[s][d] = sum_k emb_W[k][seq[k][s]][d] ----------------
__global__ __launch_bounds__(256) void embed_kernel(const int* __restrict__ seq,
                                                    const float* __restrict__ embW,
                                                    float* __restrict__ x) {
    int s = blockIdx.x, t = threadIdx.x;
    f32x4 acc = (f32x4)0.f;
#pragma unroll
    for (int k = 0; k < KTOK; ++k) {
        int tok = seq[k * S + s];
        const f32x4 v = *(const f32x4*)&embW[((size_t)k * CARD + tok) * D + t * 4];
        acc += v;
    }
    *(f32x4*)&x[(size_t)s * D + t * 4] = acc;
}

// ---------------- RMSNorm over rows of length D, bf16 output ----------------
__global__ __launch_bounds__(256) void rmsnorm_kernel(const float* __restrict__ x,
                                                      const float* __restrict__ w,
                                                      unsigned short* __restrict__ o) {
    int row = blockIdx.x, t = threadIdx.x;
    f32x4 v = *(const f32x4*)&x[(size_t)row * D + t * 4];
    float ss = v[0]*v[0] + v[1]*v[1] + v[2]*v[2] + v[3]*v[3];
#pragma unroll
    for (int off = 32; off >= 1; off >>= 1) ss += __shfl_xor(ss, off);
    __shared__ float red[4];
    int wave = t >> 6, lane = t & 63;
    if (lane == 0) red[wave] = ss;
    __syncthreads();
    ss = red[0] + red[1] + red[2] + red[3];
    float rs = rsqrtf(ss * (1.f / D) + 1e-5f);
    f32x4 wv = *(const f32x4*)&w[t * 4];
    unsigned long long pk = 0;
#pragma unroll
    for (int j = 0; j < 4; ++j)
        pk |= (unsigned long long)f2bf(v[j] * rs * wv[j]) << (16 * j);
    *(unsigned long long*)&o[(size_t)row * D + t * 4] = pk;
}

// ------- out_proj reduce (2 partials) + residual add + RMSNorm (fused) -------
__global__ __launch_bounds__(256) void outred_rms_kernel(const float* __restrict__ part,
                                                         const float* __restrict__ xin,
                                                         float* __restrict__ xout,
                                                         const float* __restrict__ w,
                                                         unsigned short* __restrict__ o) {
    int row = blockIdx.x, t = threadIdx.x;
    size_t base = (size_t)row * D + t * 4;
    f32x4 v = *(const f32x4*)&xin[base];
#pragma unroll
    for (int j = 0; j < 2; ++j)
        v += *(const f32x4*)&part[(size_t)j * (S * D) + base];
    *(f32x4*)&xout[base] = v;
    float ss = v[0]*v[0] + v[1]*v[1] + v[2]*v[2] + v[3]*v[3];
#pragma unroll
    for (int off = 32; off >= 1; off >>= 1) ss += __shfl_xor(ss, off);
    __shared__ float red[4];
    int wave = t >> 6, lane = t & 63;
    if (lane == 0) red[wave] = ss;
    __syncthreads();
    ss = red[0] + red[1] + red[2] + red[3];
    float rs = rsqrtf(ss * (1.f / D) + 1e-5f);
    f32x4 wv = *(const f32x4*)&w[t * 4];
    unsigned long long pk = 0;
#pragma unroll
    for (int j = 0; j < 4; ++j)
        pk |= (unsigned long long)f2bf(v[j] * rs * wv[j]) << (16 * j);
    *(unsigned long long*)&o[base] = pk;
}

// ------- x_proj reduce: ssm = sum of 16 partial slabs; also bf16 copy -------
__global__ __launch_bounds__(256) void ssm_reduce_kernel(const float* __restrict__ part,
                                                         float* __restrict__ ssm,
                                                         unsigned short* __restrict__ ssmb) {
    int i = blockIdx.x * 256 + threadIdx.x;    // < S*XPD
    float a = 0.f;
#pragma unroll
    for (int j = 0; j < 16; ++j)
        a += part[(size_t)j * (S * XPD) + i];
    ssm[i] = a;
    ssmb[i] = f2bf(a);
}

// ---------- causal depthwise conv1d (k=4) + bias + silu (bf16 out) ----------
__global__ __launch_bounds__(256) void conv_silu_kernel(const float* __restrict__ proj,
                                                        const float* __restrict__ cw,
                                                        const float* __restrict__ cb,
                                                        unsigned short* __restrict__ ub) {
    int idx = blockIdx.x * 256 + threadIdx.x;   // s*DI + c
    int s = idx >> 11, c = idx & (DI - 1);
    f32x4 w = *(const f32x4*)&cw[c * 4];
    float acc = cb[c];
#pragma unroll
    for (int t = 0; t < 4; ++t) {
        int ss = s - 3 + t;
        if (ss >= 0) acc = fmaf(w[t], proj[(size_t)ss * 4096 + c], acc);
    }
    ub[idx] = f2bf(acc * (1.f / (1.f + __expf(-acc))));
}

// ------- scan2 + fused dt-projection; ushort4 u-staging; serial unrolls 8/4 (optimum) -------
// block: 1024 thr = 16 chunks x 4 d x 16 n; grid = DI/4 = 512 blocks. LDS 56KB, 2 blocks/CU.
__global__ __launch_bounds__(1024, 2) void scan2_kernel(const unsigned short* __restrict__ ssmb,
                                                        const unsigned short* __restrict__ dtWb,
                                                        const float* __restrict__ dtb,
                                                        const unsigned short* __restrict__ ub,
                                                        const float* __restrict__ ssm,
                                                        const float* __restrict__ proj,
                                                        const float* __restrict__ A_log,
                                                        const float* __restrict__ Dsk,
                                                        unsigned short* __restrict__ yfb) {
    __shared__ float sdu[S * 4 * 2];   // [s][dl][{dt,u}]  32KB
    __shared__ float sP[1024], sQ[1024];
    __shared__ float sy[S * 4];        // ungated y        16KB

    const int tid = threadIdx.x;
    const int d0 = blockIdx.x * 4;
    const int chunk = tid >> 6;        // wave index = chunk (16 chunks of 64 steps)
    const int lane = tid & 63;
    const int dl = (tid >> 4) & 3;
    const int n = tid & 15;
    const int sbase = chunk * 64;

    // stage u: one 8B ushort4 load per thread (s = tid, all 4 channels)
    {
        us4 uv = *(const us4*)&ub[(size_t)tid * DI + d0];
#pragma unroll
        for (int j = 0; j < 4; ++j)
            sdu[(tid * 4 + j) * 2 + 1] = bf2f(uv[j]);
    }

    // dt = softplus(ssmb[:, :64] @ dtWb[d0..d0+3]^T + dtb) — per wave, own 64 s-rows.
    {
        const int lr = lane & 15;
        const int lk = (lane >> 4) << 3;
        f32x4 dacc[4];
#pragma unroll
        for (int m = 0; m < 4; ++m) dacc[m] = (f32x4)0.f;
        bf16x8 wf0 = *(const bf16x8*)&dtWb[(size_t)(d0 + lr) * DTR + lk];
        bf16x8 wf1 = *(const bf16x8*)&dtWb[(size_t)(d0 + lr) * DTR + 32 + lk];
#pragma unroll
        for (int m = 0; m < 4; ++m) {
            const unsigned short* arow = &ssmb[(size_t)(sbase + m * 16 + lr) * XPD];
            bf16x8 a0 = *(const bf16x8*)&arow[lk];
            bf16x8 a1 = *(const bf16x8*)&arow[32 + lk];
            dacc[m] = __builtin_amdgcn_mfma_f32_16x16x32_bf16(a0, wf0, dacc[m], 0, 0, 0);
            dacc[m] = __builtin_amdgcn_mfma_f32_16x16x32_bf16(a1, wf1, dacc[m], 0, 0, 0);
        }
        if (lr < 4) {
            float bias = dtb[d0 + lr];
            const int rb = (lane >> 4) << 2;
#pragma unroll
            for (int m = 0; m < 4; ++m)
#pragma unroll
                for (int j = 0; j < 4; ++j) {
                    int sl = sbase + m * 16 + rb + j;
                    sdu[(sl * 4 + lr) * 2 + 0] = fsoftplus(dacc[m][j] + bias);
                }
        }
    }
    const float Av = -__expf(A_log[(d0 + dl) * NSTATE + n]);
    const float Dv = Dsk[d0 + dl];
    __syncthreads();

    // pass A: local scan from zero + product of dA (unroll 8: batch loads, overlap exps)
    float h = 0.f, P = 1.f;
#pragma unroll 8
    for (int i = 0; i < 64; ++i) {
        int s = sbase + i;
        float2 du = *(const float2*)&sdu[(s * 4 + dl) * 2];
        float Bs  = ssm[s * XPD + DTR + n];
        float dA  = __expf(du.x * Av);
        P *= dA;
        h = fmaf(dA, h, du.x * du.y * Bs);
    }
    const int pqb = (dl * 16 + n) * 16;
    sP[pqb + chunk] = P;
    sQ[pqb + chunk] = h;
    __syncthreads();
    float hi = 0.f;
    for (int j = 0; j < chunk; ++j) hi = fmaf(sP[pqb + j], hi, sQ[pqb + j]);
    // pass B: true scan, DPP tree-sum (unroll 4: overlap 4 independent DPP chains)
    h = hi;
#pragma unroll 4
    for (int i = 0; i < 64; ++i) {
        int s = sbase + i;
        float2 du = *(const float2*)&sdu[(s * 4 + dl) * 2];
        float Bs  = ssm[s * XPD + DTR + n];
        float Cs  = ssm[s * XPD + DTR + NSTATE + n];
        float dA  = __expf(du.x * Av);
        h = fmaf(dA, h, du.x * du.y * Bs);
        float pc = h * Cs;
        pc = dpp_add<0xB1>(pc);    // quad_perm xor1
        pc = dpp_add<0x4E>(pc);    // quad_perm xor2
        pc = dpp_add<0x124>(pc);   // row_ror:4
        pc = dpp_add<0x128>(pc);   // row_ror:8 -> full 16-lane sum
        if (n == 0)
            sy[s * 4 + dl] = pc + du.y * Dv;
    }
    __syncthreads();
    // epilogue: gate + store, batched (thread = s row)
    {
        int s = tid;
        f32x4 yv = *(const f32x4*)&sy[s * 4];
        f32x4 g  = *(const f32x4*)&proj[(size_t)s * 4096 + 2048 + d0];
        unsigned long long pk = 0;
#pragma unroll
        for (int j = 0; j < 4; ++j)
            pk |= (unsigned long long)f2bf(yv[j] * fsilu(g[j])) << (16 * j);
        *(unsigned long long*)&yfb[(size_t)s * DI + d0] = pk;
    }
}

// ---------------- GEMM: C(1024 x N) = A(1024 x K, lda) * Wb(N x K)^T ----------------
// bf16 MFMA 16x16x32, (MR*32)x(NR*32) tile, 4 waves (2x2). LDS XOR-swizzled.
// EPI: 0 store, 1 softplus(acc+bias), 3 bias+store z-batched, 5 partial-slab store (split-K)
// ABF16: A bf16 (gload_lds) else fp32 (reg-stage+convert)
// DBUF: 3-buffer, prefetch-distance-2, counted-vmcnt pipeline (BM in {64,128}, BN=128, bf16 A)
template<int MR, int NR, int EPI, int KSPLIT, int ABF16, int DBUF>
__global__ __launch_bounds__(256) void gemm_bt(const void* __restrict__ Av, int lda,
                                               const unsigned short* __restrict__ W,
                                               float* __restrict__ C,
                                               int K, int N,
                                               const float* __restrict__ bias) {
    constexpr int BM = MR * 32;
    constexpr int BN = NR * 32;
    static_assert(DBUF == 0 || ((BM == 64 || BM == 128) && BN == 128 && ABF16 == 1), "dbuf shape");
    constexpr int NBUF = DBUF ? 3 : 1;
    __shared__ unsigned short As[NBUF][BM][32];
    __shared__ unsigned short Ws[NBUF][BN][32];
    const int tid = threadIdx.x;
    const int lane = tid & 63;
    const int wave = tid >> 6;
    const int wr = wave >> 1, wc = wave & 1;
    const int m0 = blockIdx.y * BM;
    const int n0 = blockIdx.x * BN;
    const unsigned short* Wp = W;
    const float* biasp = bias;
    float* Cp = C;
    if (EPI == 3) {
        size_t z = blockIdx.z;
        Wp += z * (size_t)N * K;
        Cp += z * (size_t)1024 * N;
        biasp += z * N;
    }
    if (EPI == 5)
        Cp = C + (size_t)blockIdx.z * 1024 * N;
    f32x4 acc[MR][NR];
#pragma unroll
    for (int m = 0; m < MR; ++m)
#pragma unroll
        for (int n = 0; n < NR; ++n) acc[m][n] = (f32x4)0.f;

    const int lr = lane & 15;
    const int lkp = (((lane >> 4) ^ ((lr >> 1) & 3)) << 3);
    const int grow = lane >> 2;
    const int gcol = (((lane & 3) ^ ((lane >> 3) & 3)) << 3);

    const int kc = (KSPLIT > 1) ? blockIdx.z : 0;
    const int Kc = K / KSPLIT;
    const int kbeg = kc * Kc;

    if constexpr (DBUF) {
        const unsigned short* Ab = (const unsigned short*)Av;
        const int nt = Kc >> 5;
        constexpr int L = BM / 64 + 2;          // per-thread gloads per tile
        auto ISSUE = [&](int t, int buf) {
            const int k0 = kbeg + t * 32;
#pragma unroll
            for (int u2 = wave; u2 < BM / 16; u2 += 4)
                gload_lds16(&Ab[(size_t)(m0 + u2 * 16 + grow) * lda + k0 + gcol],
                            &As[buf][u2 * 16][0]);
#pragma unroll
            for (int u2 = wave; u2 < BN / 16; u2 += 4)
                gload_lds16(&Wp[(size_t)(n0 + u2 * 16 + grow) * K + k0 + gcol],
                            &Ws[buf][u2 * 16][0]);
        };
        ISSUE(0, 0);
        if (nt > 1) ISSUE(1, 1);
        int nb = 2;
        int cb2 = 0;
        for (int t = 0; t < nt; ++t) {
            if (t + 2 < nt) {
                ISSUE(t + 2, nb);
                if (++nb == 3) nb = 0;
            }
            const int rem = nt - 1 - t;
            if (rem >= 2)      wait_vm<2 * L>();
            else if (rem == 1) wait_vm<L>();
            else               wait_vm<0>();
            __builtin_amdgcn_s_barrier();
            bf16x8 af[MR], wf[NR];
#pragma unroll
            for (int m = 0; m < MR; ++m)
                af[m] = *(const bf16x8*)&As[cb2][wr * (MR * 16) + m * 16 + lr][lkp];
#pragma unroll
            for (int n = 0; n < NR; ++n)
                wf[n] = *(const bf16x8*)&Ws[cb2][wc * (NR * 16) + n * 16 + lr][lkp];
            asm volatile("s_waitcnt lgkmcnt(0)" ::: "memory");
            __builtin_amdgcn_s_barrier();
            if (++cb2 == 3) cb2 = 0;
#pragma unroll
            for (int m = 0; m < MR; ++m)
#pragma unroll
                for (int n = 0; n < NR; ++n)
                    acc[m][n] = __builtin_amdgcn_mfma_f32_16x16x32_bf16(af[m], wf[n], acc[m][n], 0, 0, 0);
        }
    } else {
        for (int k0 = kbeg; k0 < kbeg + Kc; k0 += 32) {
            __syncthreads();
            if (ABF16) {
                const unsigned short* Ab = (const unsigned short*)Av;
#pragma unroll
                for (int u2 = wave; u2 < BM / 16; u2 += 4)
                    gload_lds16(&Ab[(size_t)(m0 + u2 * 16 + grow) * lda + k0 + gcol],
                                &As[0][u2 * 16][0]);
            } else {
                const float* Af = (const float*)Av;
#pragma unroll
                for (int i = 0; i < BM / 32; ++i) {
                    int idx = tid + i * 256;
                    int row = idx >> 3, c4 = (idx & 7) << 2;
                    f32x4 v = *(const f32x4*)&Af[(size_t)(m0 + row) * lda + k0 + c4];
                    unsigned long long pk = (unsigned long long)f2bf(v[0])
                                          | ((unsigned long long)f2bf(v[1]) << 16)
                                          | ((unsigned long long)f2bf(v[2]) << 32)
                                          | ((unsigned long long)f2bf(v[3]) << 48);
                    int sl = (idx & 7) >> 1, hf = (idx & 7) & 1;
                    int p = sl ^ ((row >> 1) & 3);
                    *(unsigned long long*)&As[0][row][p * 8 + hf * 4] = pk;
                }
            }
#pragma unroll
            for (int u2 = wave; u2 < BN / 16; u2 += 4)
                gload_lds16(&Wp[(size_t)(n0 + u2 * 16 + grow) * K + k0 + gcol],
                            &Ws[0][u2 * 16][0]);
            __syncthreads();
            bf16x8 af[MR], wf[NR];
#pragma unroll
            for (int m = 0; m < MR; ++m)
                af[m] = *(const bf16x8*)&As[0][wr * (MR * 16) + m * 16 + lr][lkp];
#pragma unroll
            for (int n = 0; n < NR; ++n)
                wf[n] = *(const bf16x8*)&Ws[0][wc * (NR * 16) + n * 16 + lr][lkp];
#pragma unroll
            for (int m = 0; m < MR; ++m)
#pragma unroll
                for (int n = 0; n < NR; ++n)
                    acc[m][n] = __builtin_amdgcn_mfma_f32_16x16x32_bf16(af[m], wf[n], acc[m][n], 0, 0, 0);
        }
    }

    const int mo = m0 + wr * (MR * 16);
    const int no = n0 + wc * (NR * 16);
    const int rbase = (lane >> 4) << 2;
#pragma unroll
    for (int m = 0; m < MR; ++m) {
#pragma unroll
        for (int n = 0; n < NR; ++n) {
            int col = no + n * 16 + lr;
#pragma unroll
            for (int j = 0; j < 4; ++j) {
                int row = mo + m * 16 + rbase + j;
                float v = acc[m][n][j];
                if (EPI == 1) v = fsoftplus(v + biasp[col]);
                else if (EPI == 3) v += biasp[col];
                Cp[(size_t)row * N + col] = v;
            }
        }
    }
}

// per-layer weight element counts
#define IN_E   ((size_t)4096 * 1024)
#define OUT_E  ((size_t)1024 * 2048)
#define X_E    ((size_t)XPD * 2048)
#define DT_E   ((size_t)2048 * 64)
#define HEAD_E ((size_t)KTOK * CARD * 1024)

extern "C" void kernel_launch(void* const* d_in, const int* in_sizes, int n_in,
                              void* d_out, int out_size, void* d_ws, size_t ws_size,
                              hipStream_t stream) {
    const int*   seq     = (const int*)d_in[0];
    const float* embW    = (const float*)d_in[1];
    const float* norm_w  = (const float*)d_in[2];
    const float* in_W    = (const float*)d_in[3];
    const float* conv_w  = (const float*)d_in[4];
    const float* conv_b  = (const float*)d_in[5];
    const float* x_W     = (const float*)d_in[6];
    const float* dt_W    = (const float*)d_in[7];
    const float* dt_b    = (const float*)d_in[8];
    const float* A_log   = (const float*)d_in[9];
    const float* D_skip  = (const float*)d_in[10];
    const float* out_W   = (const float*)d_in[11];
    const float* normf_w = (const float*)d_in[12];
    const float* head_W  = (const float*)d_in[13];
    const float* head_b  = (const float*)d_in[14];

    float* ws   = (float*)d_ws;
    float* x    = ws;                                  // S*D f32
    float* proj = x    + (size_t)S * D;                // S*4096 f32 (alias: out_proj partials 2x S*D)
    float* ssm  = proj + (size_t)S * 4096;             // S*96 (pad 128) f32
    float* xpart = ssm + (size_t)S * 128;              // 16 slabs of S*XPD f32 (6MB; region is S*DI f32)
    unsigned short* hnb  = (unsigned short*)(xpart + (size_t)S * DI);  // S*D bf16
    unsigned short* ub   = hnb  + (size_t)S * D;                       // S*DI bf16
    unsigned short* yfb  = ub   + (size_t)S * DI;                      // S*DI bf16
    unsigned short* ssmb = yfb  + (size_t)S * DI;                      // S*128 bf16
    unsigned short* wbase = ssmb + (size_t)S * 128;
    float* opart = proj;   // 2 slabs of S*D (8MB) — proj dead after scan reads gate

    size_t actBytes = (char*)wbase - (char*)ws;
    size_t perLayerE = IN_E + OUT_E + X_E + DT_E;
    bool bulk = ws_size >= actBytes + (48 * perLayerE + HEAD_E) * 2 + 256;

    unsigned short* inWb, *outWb, *xWb, *dtWb, *headWb;
    size_t strIn, strOut, strX, strDt;
    if (bulk) {
        inWb  = wbase;
        outWb = inWb  + 48 * IN_E;
        xWb   = outWb + 48 * OUT_E;
        dtWb  = xWb   + 48 * X_E;
        headWb = dtWb + 48 * DT_E;
        strIn = IN_E; strOut = OUT_E; strX = X_E; strDt = DT_E;
    } else {
        inWb  = wbase;
        outWb = inWb  + IN_E;
        xWb   = outWb + OUT_E;
        dtWb  = xWb   + X_E;
        headWb = dtWb + DT_E;
        strIn = strOut = strX = strDt = 0;
    }

    embed_kernel<<<S, 256, 0, stream>>>(seq, embW, x);
    rmsnorm_kernel<<<S, 256, 0, stream>>>(x, norm_w, hnb);   // layer 0 norm
    cvt4_kernel<<<(unsigned)(HEAD_E / 8 / 256), 256, 0, stream>>>(
        head_W, (long)(HEAD_E / 8), nullptr, 0, nullptr, 0, nullptr, 0,
        headWb, nullptr, nullptr, nullptr);
    if (bulk) {
        long na = (long)(48 * IN_E / 8), nb = (long)(48 * OUT_E / 8);
        long nc = (long)(48 * X_E / 8),  nd = (long)(48 * DT_E / 8);
        cvt4_kernel<<<(unsigned)((na + nb + nc + nd) / 256), 256, 0, stream>>>(
            in_W, na, out_W, nb, x_W, nc, dt_W, nd, inWb, outWb, xWb, dtWb);
    }

    for (int l = 0; l < NL; ++l) {
        if (!bulk) {
            cvt4_kernel<<<(unsigned)(perLayerE / 8 / 256), 256, 0, stream>>>(
                in_W + (size_t)l * IN_E, (long)(IN_E / 8),
                out_W + (size_t)l * OUT_E, (long)(OUT_E / 8),
                x_W + (size_t)l * X_E, (long)(X_E / 8),
                dt_W + (size_t)l * DT_E, (long)(DT_E / 8),
                inWb, outWb, xWb, dtWb);
        }
        // in_proj: 64x128 tiles, 512 blocks (2/CU), 3-deep pipeline
        gemm_bt<2, 4, 0, 1, 1, 1><<<dim3(32, 16), 256, 0, stream>>>(hnb, D,
            inWb + (size_t)l * strIn, proj, D, 4096, nullptr);
        conv_silu_kernel<<<(S * DI) / 256, 256, 0, stream>>>(proj,
            conv_w + (size_t)l * DI * 4, conv_b + (size_t)l * DI, ub);
        // x_proj: bf16 A, 64x96 tiles, KSPLIT=16 -> 256 blocks
        gemm_bt<2, 3, 5, 16, 1, 0><<<dim3(1, 16, 16), 256, 0, stream>>>(ub, DI,
            xWb + (size_t)l * strX, xpart, DI, XPD, nullptr);
        ssm_reduce_kernel<<<(S * XPD) / 256, 256, 0, stream>>>(xpart, ssm, ssmb);
        scan2_kernel<<<DI / 4, 1024, 0, stream>>>(ssmb, dtWb + (size_t)l * strDt,
            dt_b + (size_t)l * DI, ub, ssm, proj,
            A_log + (size_t)l * DI * NSTATE, D_skip + (size_t)l * DI, yfb);
        // out_proj: 64x128 tiles, KSPLIT=2 -> 256 blocks, 2 partial slabs
        gemm_bt<2, 4, 5, 2, 1, 1><<<dim3(8, 16, 2), 256, 0, stream>>>(yfb, DI,
            outWb + (size_t)l * strOut, opart, DI, D, nullptr);
        outred_rms_kernel<<<S, 256, 0, stream>>>(opart, x, x,
            (l + 1 < NL) ? (norm_w + (size_t)(l + 1) * D) : normf_w, hnb);
    }

    gemm_bt<4, 4, 3, 1, 1, 1><<<dim3(16, 8, 4), 256, 0, stream>>>(hnb, D, headWb,
        (float*)d_out, D, CARD, head_b);
}